// Round 16
// baseline (35.443 us; speedup 1.0000x reference)
//
#include <hip/hip_runtime.h>

#define EPS 1e-8f

// Shapes fixed per reference: x [B=8, N=8192, D=512] fp32, scalar fp32 out.
#define B_DIM 8
#define N_DIM 8192
#define D_DIM 512
#define CHUNKS 64    // K1 grid = B*CHUNKS = 512 blocks x 16 waves = 32 waves/CU
#define FIX_SCALE 1099511627776.0   // 2^40 fixed-point scale for deterministic sum

typedef float fx4 __attribute__((ext_vector_type(4)));

// K1: 1024 threads (16 waves). Each wave: 8 rows, 4 rows/iteration, register
// double-buffer (unchanged from round 15). Lane l owns d-slice [8l,8l+8).
// Block 0 zeroes acc/ticket (consumed by K2 -> stream order suffices).
__global__ __launch_bounds__(1024) void k1_partial(const float* __restrict__ x,
                                                   float* __restrict__ partial,
                                                   unsigned long long* __restrict__ ctl) {
    if (blockIdx.x == 0 && threadIdx.x < 2) ctl[threadIdx.x] = 0ULL;

    constexpr int rowsPerChunk = N_DIM / CHUNKS;    // 128
    constexpr int rowsPerWave  = rowsPerChunk / 16; // 8
    constexpr int ITERS        = rowsPerWave / 4;   // 2

    const int blk   = blockIdx.x;
    const int b     = blk >> 6;            // / CHUNKS
    const int chunk = blk & (CHUNKS - 1);
    const int wave  = threadIdx.x >> 6;    // 0..15
    const int lane  = threadIdx.x & 63;

    const long long rowStart = (long long)b * N_DIM
                             + (long long)chunk * rowsPerChunk
                             + (long long)wave * rowsPerWave;

    float accv[8];
    #pragma unroll
    for (int k = 0; k < 8; ++k) accv[k] = 0.0f;

    const float* base = x + rowStart * D_DIM + lane * 8;

    fx4 v[2][4][2];

    #pragma unroll
    for (int i = 0; i < 4; ++i) {
        v[0][i][0] = *(const fx4*)(base + i * D_DIM);
        v[0][i][1] = *(const fx4*)(base + i * D_DIM + 4);
    }
    base += 4 * D_DIM;

    #pragma unroll
    for (int it = 0; it < ITERS; ++it) {
        const int cur = it & 1;
        const int nxt = cur ^ 1;

        if (it < ITERS - 1) {
            #pragma unroll
            for (int i = 0; i < 4; ++i) {
                v[nxt][i][0] = *(const fx4*)(base + i * D_DIM);
                v[nxt][i][1] = *(const fx4*)(base + i * D_DIM + 4);
            }
            base += 4 * D_DIM;
        }

        float ss[4];
        #pragma unroll
        for (int i = 0; i < 4; ++i) {
            ss[i] = v[cur][i][0].x*v[cur][i][0].x + v[cur][i][0].y*v[cur][i][0].y
                  + v[cur][i][0].z*v[cur][i][0].z + v[cur][i][0].w*v[cur][i][0].w
                  + v[cur][i][1].x*v[cur][i][1].x + v[cur][i][1].y*v[cur][i][1].y
                  + v[cur][i][1].z*v[cur][i][1].z + v[cur][i][1].w*v[cur][i][1].w;
        }

        #pragma unroll
        for (int off = 1; off < 64; off <<= 1) {
            #pragma unroll
            for (int i = 0; i < 4; ++i) ss[i] += __shfl_xor(ss[i], off);
        }

        #pragma unroll
        for (int i = 0; i < 4; ++i) {
            const float inv = 1.0f / fmaxf(sqrtf(ss[i]), EPS);
            accv[0] += v[cur][i][0].x * inv;
            accv[1] += v[cur][i][0].y * inv;
            accv[2] += v[cur][i][0].z * inv;
            accv[3] += v[cur][i][0].w * inv;
            accv[4] += v[cur][i][1].x * inv;
            accv[5] += v[cur][i][1].y * inv;
            accv[6] += v[cur][i][1].z * inv;
            accv[7] += v[cur][i][1].w * inv;
        }
    }

    // combine the 16 waves' partials deterministically via LDS
    __shared__ float lds[16][D_DIM];
    float* dst = &lds[wave][lane * 8];
    #pragma unroll
    for (int k = 0; k < 8; ++k) dst[k] = accv[k];
    __syncthreads();

    if (threadIdx.x < D_DIM) {
        const int d = threadIdx.x;
        float s = 0.0f;
        #pragma unroll
        for (int w = 0; w < 16; ++w) s += lds[w][d];
        partial[(long long)blk * D_DIM + d] = s;
    }
}

// K2: 64 blocks = (b, g) with g = d-group of 64 d's; 256 threads.
// Thread (q=tid>>4 in 0..15, quad=tid&15) sums chunks 4q..4q+3 at d-quad
// g*64+quad*4 (4 contiguous fx4 loads, one latency round). LDS tree 16->1,
// square, 16-lane reduce -> block ssq. Fixed-point u64 atomic add
// (order-independent = deterministic); ticket-63 block writes the scalar.
__global__ __launch_bounds__(256) void k2_batch(const float* __restrict__ partial,
                                                unsigned long long* __restrict__ acc,
                                                unsigned long long* __restrict__ ticket,
                                                float* __restrict__ out) {
    const int b    = blockIdx.x >> 3;
    const int g    = blockIdx.x & 7;
    const int quad = threadIdx.x & 15;   // d-quad within group
    const int q    = threadIdx.x >> 4;   // 0..15 chunk-set

    const float* p = partial + (long long)b * CHUNKS * D_DIM
                   + (long long)g * 64 + quad * 4;

    const long long cbase = (long long)q * 4;
    fx4 s0 = *(const fx4*)(p + (cbase + 0) * D_DIM);
    fx4 s1 = *(const fx4*)(p + (cbase + 1) * D_DIM);
    fx4 s2 = *(const fx4*)(p + (cbase + 2) * D_DIM);
    fx4 s3 = *(const fx4*)(p + (cbase + 3) * D_DIM);
    const fx4 s = (s0 + s1) + (s2 + s3);

    __shared__ fx4 lds[16][16];
    lds[q][quad] = s;
    __syncthreads();

    if (q < 4) {
        lds[q][quad] = (lds[q][quad] + lds[q + 4][quad])
                     + (lds[q + 8][quad] + lds[q + 12][quad]);
    }
    __syncthreads();

    if (threadIdx.x < 16) {
        const fx4 t = (lds[0][quad] + lds[1][quad])
                    + (lds[2][quad] + lds[3][quad]);
        float v = t.x*t.x + t.y*t.y + t.z*t.z + t.w*t.w;
        #pragma unroll
        for (int off = 1; off < 16; off <<= 1) v += __shfl_xor(v, off);

        if (threadIdx.x == 0) {
            const long long q64 = (long long)((double)v * FIX_SCALE);
            atomicAdd(acc, (unsigned long long)q64);
            __threadfence();
            const unsigned long long t63 = atomicAdd(ticket, 1ULL);
            if (t63 == (B_DIM * 8 - 1)) {
                const unsigned long long totu = atomicAdd(acc, 0ULL);
                const double tot_d = (double)(long long)totu / FIX_SCALE;
                out[0] = (float)(tot_d / ((double)N_DIM * (double)N_DIM * (double)B_DIM));
            }
        }
    }
}

extern "C" void kernel_launch(void* const* d_in, const int* in_sizes, int n_in,
                              void* d_out, int out_size, void* d_ws, size_t ws_size,
                              hipStream_t stream) {
    const float* x = (const float*)d_in[0];
    float* out = (float*)d_out;

    float* partial = (float*)d_ws;                                  // 8*64*512 floats = 1 MB
    unsigned long long* ctl = (unsigned long long*)((char*)d_ws +
                              (size_t)B_DIM * CHUNKS * D_DIM * sizeof(float));

    k1_partial<<<dim3(B_DIM * CHUNKS), dim3(1024), 0, stream>>>(x, partial, ctl);
    k2_batch<<<dim3(B_DIM * 8), dim3(256), 0, stream>>>(partial, ctl + 0, ctl + 1, out);
}

// Round 17
// 32.964 us; speedup vs baseline: 1.0752x; 1.0752x over previous
//
#include <hip/hip_runtime.h>

#define EPS 1e-8f

// Shapes fixed per reference: x [B=8, N=8192, D=512] fp32, scalar fp32 out.
#define B_DIM 8
#define N_DIM 8192
#define D_DIM 512
#define CHUNKS 256   // K1 grid = B*CHUNKS = 2048 blocks (8/CU, 32 waves/CU)
#define FIX_SCALE 1099511627776.0   // 2^40 fixed-point scale for deterministic sum

typedef float fx4 __attribute__((ext_vector_type(4)));

// K1 (proven config, R10 probe: ~23.8us incl. boundary): 256 threads (4
// waves). Each wave: 8 rows, 4 rows/iteration, register double-buffer.
// Lane l owns d-slice [8l,8l+8). Block 0 zeroes acc/ticket (consumed by K2,
// next kernel -> stream order is sufficient).
__global__ __launch_bounds__(256) void k1_partial(const float* __restrict__ x,
                                                  float* __restrict__ partial,
                                                  unsigned long long* __restrict__ ctl) {
    if (blockIdx.x == 0 && threadIdx.x < 2) ctl[threadIdx.x] = 0ULL;

    constexpr int rowsPerChunk = N_DIM / CHUNKS;   // 32
    constexpr int rowsPerWave  = rowsPerChunk / 4; // 8
    constexpr int ITERS        = rowsPerWave / 4;  // 2

    const int blk   = blockIdx.x;
    const int b     = blk >> 8;            // / CHUNKS
    const int chunk = blk & (CHUNKS - 1);
    const int wave  = threadIdx.x >> 6;    // 0..3
    const int lane  = threadIdx.x & 63;

    const long long rowStart = (long long)b * N_DIM
                             + (long long)chunk * rowsPerChunk
                             + (long long)wave * rowsPerWave;

    float accv[8];
    #pragma unroll
    for (int k = 0; k < 8; ++k) accv[k] = 0.0f;

    const float* base = x + rowStart * D_DIM + lane * 8;

    fx4 v[2][4][2];

    #pragma unroll
    for (int i = 0; i < 4; ++i) {
        v[0][i][0] = *(const fx4*)(base + i * D_DIM);
        v[0][i][1] = *(const fx4*)(base + i * D_DIM + 4);
    }
    base += 4 * D_DIM;

    #pragma unroll
    for (int it = 0; it < ITERS; ++it) {
        const int cur = it & 1;
        const int nxt = cur ^ 1;

        if (it < ITERS - 1) {
            #pragma unroll
            for (int i = 0; i < 4; ++i) {
                v[nxt][i][0] = *(const fx4*)(base + i * D_DIM);
                v[nxt][i][1] = *(const fx4*)(base + i * D_DIM + 4);
            }
            base += 4 * D_DIM;
        }

        float ss[4];
        #pragma unroll
        for (int i = 0; i < 4; ++i) {
            ss[i] = v[cur][i][0].x*v[cur][i][0].x + v[cur][i][0].y*v[cur][i][0].y
                  + v[cur][i][0].z*v[cur][i][0].z + v[cur][i][0].w*v[cur][i][0].w
                  + v[cur][i][1].x*v[cur][i][1].x + v[cur][i][1].y*v[cur][i][1].y
                  + v[cur][i][1].z*v[cur][i][1].z + v[cur][i][1].w*v[cur][i][1].w;
        }

        #pragma unroll
        for (int off = 1; off < 64; off <<= 1) {
            #pragma unroll
            for (int i = 0; i < 4; ++i) ss[i] += __shfl_xor(ss[i], off);
        }

        #pragma unroll
        for (int i = 0; i < 4; ++i) {
            const float inv = 1.0f / fmaxf(sqrtf(ss[i]), EPS);
            accv[0] += v[cur][i][0].x * inv;
            accv[1] += v[cur][i][0].y * inv;
            accv[2] += v[cur][i][0].z * inv;
            accv[3] += v[cur][i][0].w * inv;
            accv[4] += v[cur][i][1].x * inv;
            accv[5] += v[cur][i][1].y * inv;
            accv[6] += v[cur][i][1].z * inv;
            accv[7] += v[cur][i][1].w * inv;
        }
    }

    __shared__ float lds[4][D_DIM];
    float* dst = &lds[wave][lane * 8];
    #pragma unroll
    for (int k = 0; k < 8; ++k) dst[k] = accv[k];
    __syncthreads();

    for (int d = threadIdx.x; d < D_DIM; d += 256) {
        float s = lds[0][d] + lds[1][d] + lds[2][d] + lds[3][d];
        partial[(long long)blk * D_DIM + d] = s;
    }
}

// K2: 128 blocks = (b, g) with g<16 d-groups of 32 d's; 512 threads.
// Thread (q=tid>>3 in 0..63, quad=tid&7) sums chunks 4q..4q+3 at d-quad
// g*32+quad*4 (4 contiguous fx4 loads, one ILP-4 latency round). LDS tree
// 64->16->4->1 over q, square, 8-lane reduce -> block ssq. Fixed-point u64
// atomic add (order-independent = deterministic, 128 same-address atomics
// -- R11 measured 64 as ~free); ticket-127 block writes the final scalar.
__global__ __launch_bounds__(512) void k2_batch(const float* __restrict__ partial,
                                                unsigned long long* __restrict__ acc,
                                                unsigned long long* __restrict__ ticket,
                                                float* __restrict__ out) {
    const int b    = blockIdx.x >> 4;
    const int g    = blockIdx.x & 15;
    const int quad = threadIdx.x & 7;    // d-quad within 32-d group
    const int q    = threadIdx.x >> 3;   // 0..63 chunk-set

    const float* p = partial + (long long)b * CHUNKS * D_DIM
                   + (long long)g * 32 + quad * 4;

    const long long cbase = (long long)q * 4;
    fx4 s0 = *(const fx4*)(p + (cbase + 0) * D_DIM);
    fx4 s1 = *(const fx4*)(p + (cbase + 1) * D_DIM);
    fx4 s2 = *(const fx4*)(p + (cbase + 2) * D_DIM);
    fx4 s3 = *(const fx4*)(p + (cbase + 3) * D_DIM);
    const fx4 s = (s0 + s1) + (s2 + s3);

    __shared__ fx4 lds[64][8];
    lds[q][quad] = s;
    __syncthreads();

    // stage 1: 64 -> 16 rows
    if (q < 16) {
        lds[q][quad] = (lds[q][quad] + lds[q + 16][quad])
                     + (lds[q + 32][quad] + lds[q + 48][quad]);
    }
    __syncthreads();
    // stage 2: 16 -> 4 rows
    if (q < 4) {
        lds[q][quad] = (lds[q][quad] + lds[q + 4][quad])
                     + (lds[q + 8][quad] + lds[q + 12][quad]);
    }
    __syncthreads();
    // stage 3: 4 -> 1, square, 8-lane reduce (threads 0..7)
    if (threadIdx.x < 8) {
        const fx4 t = (lds[0][quad] + lds[1][quad])
                    + (lds[2][quad] + lds[3][quad]);
        float v = t.x*t.x + t.y*t.y + t.z*t.z + t.w*t.w;
        #pragma unroll
        for (int off = 1; off < 8; off <<= 1) v += __shfl_xor(v, off);

        if (threadIdx.x == 0) {
            const long long q64 = (long long)((double)v * FIX_SCALE);
            atomicAdd(acc, (unsigned long long)q64);
            __threadfence();
            const unsigned long long tk = atomicAdd(ticket, 1ULL);
            if (tk == (B_DIM * 16 - 1)) {
                const unsigned long long totu = atomicAdd(acc, 0ULL);
                const double tot_d = (double)(long long)totu / FIX_SCALE;
                out[0] = (float)(tot_d / ((double)N_DIM * (double)N_DIM * (double)B_DIM));
            }
        }
    }
}

extern "C" void kernel_launch(void* const* d_in, const int* in_sizes, int n_in,
                              void* d_out, int out_size, void* d_ws, size_t ws_size,
                              hipStream_t stream) {
    const float* x = (const float*)d_in[0];
    float* out = (float*)d_out;

    float* partial = (float*)d_ws;                                  // 8*256*512 floats = 4 MB
    unsigned long long* ctl = (unsigned long long*)((char*)d_ws +
                              (size_t)B_DIM * CHUNKS * D_DIM * sizeof(float));

    k1_partial<<<dim3(B_DIM * CHUNKS), dim3(256), 0, stream>>>(x, partial, ctl);
    k2_batch<<<dim3(B_DIM * 16), dim3(512), 0, stream>>>(partial, ctl + 0, ctl + 1, out);
}

// Round 18
// 32.264 us; speedup vs baseline: 1.0985x; 1.0217x over previous
//
#include <hip/hip_runtime.h>

#define EPS 1e-8f

// Shapes fixed per reference: x [B=8, N=8192, D=512] fp32, scalar fp32 out.
#define B_DIM 8
#define N_DIM 8192
#define D_DIM 512
#define CHUNKS 256   // K1 grid = B*CHUNKS = 2048 blocks (8/CU, 32 waves/CU)
#define FIX_SCALE 1099511627776.0   // 2^40 fixed-point scale for deterministic sum

typedef float fx4 __attribute__((ext_vector_type(4)));

// K1 (proven config, R10 probe: ~23.8us incl. boundary): 256 threads (4
// waves). Each wave: 8 rows, 4 rows/iteration, register double-buffer.
// Lane l owns d-slice [8l,8l+8). Block 0 zeroes acc/ticket (consumed by K2,
// next kernel -> stream order is sufficient).
// ROUND-18 CHANGE: partial is written with NONTEMPORAL stores so the 4 MB
// intermediate never dirties per-XCD L2 (suspected source of the ~7.7 us
// K1->K2 cost: boundary dirty-L2 flush / cross-XCD dirty-line snoop).
__global__ __launch_bounds__(256) void k1_partial(const float* __restrict__ x,
                                                  float* __restrict__ partial,
                                                  unsigned long long* __restrict__ ctl) {
    if (blockIdx.x == 0 && threadIdx.x < 2) ctl[threadIdx.x] = 0ULL;

    constexpr int rowsPerChunk = N_DIM / CHUNKS;   // 32
    constexpr int rowsPerWave  = rowsPerChunk / 4; // 8
    constexpr int ITERS        = rowsPerWave / 4;  // 2

    const int blk   = blockIdx.x;
    const int b     = blk >> 8;            // / CHUNKS
    const int chunk = blk & (CHUNKS - 1);
    const int wave  = threadIdx.x >> 6;    // 0..3
    const int lane  = threadIdx.x & 63;

    const long long rowStart = (long long)b * N_DIM
                             + (long long)chunk * rowsPerChunk
                             + (long long)wave * rowsPerWave;

    float accv[8];
    #pragma unroll
    for (int k = 0; k < 8; ++k) accv[k] = 0.0f;

    const float* base = x + rowStart * D_DIM + lane * 8;

    fx4 v[2][4][2];

    #pragma unroll
    for (int i = 0; i < 4; ++i) {
        v[0][i][0] = *(const fx4*)(base + i * D_DIM);
        v[0][i][1] = *(const fx4*)(base + i * D_DIM + 4);
    }
    base += 4 * D_DIM;

    #pragma unroll
    for (int it = 0; it < ITERS; ++it) {
        const int cur = it & 1;
        const int nxt = cur ^ 1;

        if (it < ITERS - 1) {
            #pragma unroll
            for (int i = 0; i < 4; ++i) {
                v[nxt][i][0] = *(const fx4*)(base + i * D_DIM);
                v[nxt][i][1] = *(const fx4*)(base + i * D_DIM + 4);
            }
            base += 4 * D_DIM;
        }

        float ss[4];
        #pragma unroll
        for (int i = 0; i < 4; ++i) {
            ss[i] = v[cur][i][0].x*v[cur][i][0].x + v[cur][i][0].y*v[cur][i][0].y
                  + v[cur][i][0].z*v[cur][i][0].z + v[cur][i][0].w*v[cur][i][0].w
                  + v[cur][i][1].x*v[cur][i][1].x + v[cur][i][1].y*v[cur][i][1].y
                  + v[cur][i][1].z*v[cur][i][1].z + v[cur][i][1].w*v[cur][i][1].w;
        }

        #pragma unroll
        for (int off = 1; off < 64; off <<= 1) {
            #pragma unroll
            for (int i = 0; i < 4; ++i) ss[i] += __shfl_xor(ss[i], off);
        }

        #pragma unroll
        for (int i = 0; i < 4; ++i) {
            const float inv = 1.0f / fmaxf(sqrtf(ss[i]), EPS);
            accv[0] += v[cur][i][0].x * inv;
            accv[1] += v[cur][i][0].y * inv;
            accv[2] += v[cur][i][0].z * inv;
            accv[3] += v[cur][i][0].w * inv;
            accv[4] += v[cur][i][1].x * inv;
            accv[5] += v[cur][i][1].y * inv;
            accv[6] += v[cur][i][1].z * inv;
            accv[7] += v[cur][i][1].w * inv;
        }
    }

    __shared__ float lds[4][D_DIM];
    float* dst = &lds[wave][lane * 8];
    #pragma unroll
    for (int k = 0; k < 8; ++k) dst[k] = accv[k];
    __syncthreads();

    for (int d = threadIdx.x; d < D_DIM; d += 256) {
        const float s = lds[0][d] + lds[1][d] + lds[2][d] + lds[3][d];
        __builtin_nontemporal_store(s, &partial[(long long)blk * D_DIM + d]);
    }
}

// K2 (unchanged from round 15, best benched): 64 blocks = (b, g) with g =
// d-group of 64 d's; 1024 threads. Thread (q=tid>>4 in 0..63, quad=tid&15)
// sums chunks 4q..4q+3 at d-quad g*64+quad*4 (contiguous fx4, 4-deep ILP).
// 3-stage LDS tree 64->1, square, 16-lane reduce -> block ssq. Fixed-point
// u64 atomic add (order-independent = deterministic); ticket-63 block
// writes the final scalar.
__global__ __launch_bounds__(1024) void k2_batch(const float* __restrict__ partial,
                                                 unsigned long long* __restrict__ acc,
                                                 unsigned long long* __restrict__ ticket,
                                                 float* __restrict__ out) {
    const int b    = blockIdx.x >> 3;
    const int g    = blockIdx.x & 7;
    const int quad = threadIdx.x & 15;   // d-quad within group
    const int q    = threadIdx.x >> 4;   // 0..63 chunk-set

    const float* p = partial + (long long)b * CHUNKS * D_DIM
                   + (long long)g * 64 + quad * 4;

    const long long cbase = (long long)q * 4;
    fx4 s0 = *(const fx4*)(p + (cbase + 0) * D_DIM);
    fx4 s1 = *(const fx4*)(p + (cbase + 1) * D_DIM);
    fx4 s2 = *(const fx4*)(p + (cbase + 2) * D_DIM);
    fx4 s3 = *(const fx4*)(p + (cbase + 3) * D_DIM);
    const fx4 s = (s0 + s1) + (s2 + s3);

    __shared__ fx4 lds[64][16];
    lds[q][quad] = s;
    __syncthreads();

    // stage 1: 64 -> 16 rows
    if (q < 16) {
        lds[q][quad] = (lds[q][quad] + lds[q + 16][quad])
                     + (lds[q + 32][quad] + lds[q + 48][quad]);
    }
    __syncthreads();
    // stage 2: 16 -> 4 rows
    if (q < 4) {
        lds[q][quad] = (lds[q][quad] + lds[q + 4][quad])
                     + (lds[q + 8][quad] + lds[q + 12][quad]);
    }
    __syncthreads();
    // stage 3: 4 -> 1, then square + 16-lane reduce (threads 0..15, wave 0)
    if (threadIdx.x < 16) {
        const fx4 t = (lds[0][quad] + lds[1][quad])
                    + (lds[2][quad] + lds[3][quad]);
        float v = t.x*t.x + t.y*t.y + t.z*t.z + t.w*t.w;
        #pragma unroll
        for (int off = 1; off < 16; off <<= 1) v += __shfl_xor(v, off);

        if (threadIdx.x == 0) {
            const long long q64 = (long long)((double)v * FIX_SCALE);
            atomicAdd(acc, (unsigned long long)q64);
            __threadfence();
            const unsigned long long t63 = atomicAdd(ticket, 1ULL);
            if (t63 == (B_DIM * 8 - 1)) {
                const unsigned long long totu = atomicAdd(acc, 0ULL);
                const double tot_d = (double)(long long)totu / FIX_SCALE;
                out[0] = (float)(tot_d / ((double)N_DIM * (double)N_DIM * (double)B_DIM));
            }
        }
    }
}

extern "C" void kernel_launch(void* const* d_in, const int* in_sizes, int n_in,
                              void* d_out, int out_size, void* d_ws, size_t ws_size,
                              hipStream_t stream) {
    const float* x = (const float*)d_in[0];
    float* out = (float*)d_out;

    float* partial = (float*)d_ws;                                  // 8*256*512 floats = 4 MB
    unsigned long long* ctl = (unsigned long long*)((char*)d_ws +
                              (size_t)B_DIM * CHUNKS * D_DIM * sizeof(float));

    k1_partial<<<dim3(B_DIM * CHUNKS), dim3(256), 0, stream>>>(x, partial, ctl);
    k2_batch<<<dim3(B_DIM * 8), dim3(1024), 0, stream>>>(partial, ctl + 0, ctl + 1, out);
}

// Round 19
// 30.400 us; speedup vs baseline: 1.1659x; 1.0613x over previous
//
#include <hip/hip_runtime.h>

#define EPS 1e-8f

// Shapes fixed per reference: x [B=8, N=8192, D=512] fp32, scalar fp32 out.
#define B_DIM 8
#define N_DIM 8192
#define D_DIM 512
#define CHUNKS 128   // K1 grid = B*CHUNKS = 1024 blocks x 8 waves = 32 waves/CU
#define FIX_SCALE 1099511627776.0   // 2^40 fixed-point scale for deterministic sum

typedef float fx4 __attribute__((ext_vector_type(4)));

// K1: 512 threads (8 waves, 4 blocks/CU -> 32 waves/CU, same as the proven
// 23.8us config). Each wave: 8 rows, 4 rows/iteration, register double-
// buffer (inner loop unchanged). Lane l owns d-slice [8l,8l+8).
// Partial buffer is half of round 15's (2 MB) -> tests K2-cost ~ size.
// Block 0 zeroes acc/ticket (consumed by K2 -> stream order suffices).
__global__ __launch_bounds__(512) void k1_partial(const float* __restrict__ x,
                                                  float* __restrict__ partial,
                                                  unsigned long long* __restrict__ ctl) {
    if (blockIdx.x == 0 && threadIdx.x < 2) ctl[threadIdx.x] = 0ULL;

    constexpr int rowsPerChunk = N_DIM / CHUNKS;   // 64
    constexpr int rowsPerWave  = rowsPerChunk / 8; // 8
    constexpr int ITERS        = rowsPerWave / 4;  // 2

    const int blk   = blockIdx.x;
    const int b     = blk >> 7;            // / CHUNKS
    const int chunk = blk & (CHUNKS - 1);
    const int wave  = threadIdx.x >> 6;    // 0..7
    const int lane  = threadIdx.x & 63;

    const long long rowStart = (long long)b * N_DIM
                             + (long long)chunk * rowsPerChunk
                             + (long long)wave * rowsPerWave;

    float accv[8];
    #pragma unroll
    for (int k = 0; k < 8; ++k) accv[k] = 0.0f;

    const float* base = x + rowStart * D_DIM + lane * 8;

    fx4 v[2][4][2];

    #pragma unroll
    for (int i = 0; i < 4; ++i) {
        v[0][i][0] = *(const fx4*)(base + i * D_DIM);
        v[0][i][1] = *(const fx4*)(base + i * D_DIM + 4);
    }
    base += 4 * D_DIM;

    #pragma unroll
    for (int it = 0; it < ITERS; ++it) {
        const int cur = it & 1;
        const int nxt = cur ^ 1;

        if (it < ITERS - 1) {
            #pragma unroll
            for (int i = 0; i < 4; ++i) {
                v[nxt][i][0] = *(const fx4*)(base + i * D_DIM);
                v[nxt][i][1] = *(const fx4*)(base + i * D_DIM + 4);
            }
            base += 4 * D_DIM;
        }

        float ss[4];
        #pragma unroll
        for (int i = 0; i < 4; ++i) {
            ss[i] = v[cur][i][0].x*v[cur][i][0].x + v[cur][i][0].y*v[cur][i][0].y
                  + v[cur][i][0].z*v[cur][i][0].z + v[cur][i][0].w*v[cur][i][0].w
                  + v[cur][i][1].x*v[cur][i][1].x + v[cur][i][1].y*v[cur][i][1].y
                  + v[cur][i][1].z*v[cur][i][1].z + v[cur][i][1].w*v[cur][i][1].w;
        }

        #pragma unroll
        for (int off = 1; off < 64; off <<= 1) {
            #pragma unroll
            for (int i = 0; i < 4; ++i) ss[i] += __shfl_xor(ss[i], off);
        }

        #pragma unroll
        for (int i = 0; i < 4; ++i) {
            const float inv = 1.0f / fmaxf(sqrtf(ss[i]), EPS);
            accv[0] += v[cur][i][0].x * inv;
            accv[1] += v[cur][i][0].y * inv;
            accv[2] += v[cur][i][0].z * inv;
            accv[3] += v[cur][i][0].w * inv;
            accv[4] += v[cur][i][1].x * inv;
            accv[5] += v[cur][i][1].y * inv;
            accv[6] += v[cur][i][1].z * inv;
            accv[7] += v[cur][i][1].w * inv;
        }
    }

    // combine the 8 waves' partials deterministically via LDS (16 KB)
    __shared__ float lds[8][D_DIM];
    float* dst = &lds[wave][lane * 8];
    #pragma unroll
    for (int k = 0; k < 8; ++k) dst[k] = accv[k];
    __syncthreads();

    {
        const int d = threadIdx.x;          // 512 threads = 512 d's, 1:1
        float s = 0.0f;
        #pragma unroll
        for (int w = 0; w < 8; ++w) s += lds[w][d];
        partial[(long long)blk * D_DIM + d] = s;
    }
}

// K2 (R15 structure scaled to CHUNKS=128): 64 blocks = (b, g), g = d-group
// of 64 d's; 512 threads. Thread (q=tid>>4 in 0..31, quad=tid&15) sums
// chunks 4q..4q+3 at d-quad g*64+quad*4 (contiguous fx4, 4-deep ILP).
// LDS tree 32->8->1, square, 16-lane reduce -> block ssq. Fixed-point u64
// atomic add (order-independent = deterministic); ticket-63 block writes
// the final scalar.
__global__ __launch_bounds__(512) void k2_batch(const float* __restrict__ partial,
                                                unsigned long long* __restrict__ acc,
                                                unsigned long long* __restrict__ ticket,
                                                float* __restrict__ out) {
    const int b    = blockIdx.x >> 3;
    const int g    = blockIdx.x & 7;
    const int quad = threadIdx.x & 15;   // d-quad within group
    const int q    = threadIdx.x >> 4;   // 0..31 chunk-set

    const float* p = partial + (long long)b * CHUNKS * D_DIM
                   + (long long)g * 64 + quad * 4;

    const long long cbase = (long long)q * 4;
    fx4 s0 = *(const fx4*)(p + (cbase + 0) * D_DIM);
    fx4 s1 = *(const fx4*)(p + (cbase + 1) * D_DIM);
    fx4 s2 = *(const fx4*)(p + (cbase + 2) * D_DIM);
    fx4 s3 = *(const fx4*)(p + (cbase + 3) * D_DIM);
    const fx4 s = (s0 + s1) + (s2 + s3);

    __shared__ fx4 lds[32][16];
    lds[q][quad] = s;
    __syncthreads();

    // stage 1: 32 -> 8 rows
    if (q < 8) {
        lds[q][quad] = (lds[q][quad] + lds[q + 8][quad])
                     + (lds[q + 16][quad] + lds[q + 24][quad]);
    }
    __syncthreads();
    // stage 2: 8 -> 1, square, 16-lane reduce (threads 0..15)
    if (threadIdx.x < 16) {
        const fx4 t = ((lds[0][quad] + lds[1][quad]) + (lds[2][quad] + lds[3][quad]))
                    + ((lds[4][quad] + lds[5][quad]) + (lds[6][quad] + lds[7][quad]));
        float v = t.x*t.x + t.y*t.y + t.z*t.z + t.w*t.w;
        #pragma unroll
        for (int off = 1; off < 16; off <<= 1) v += __shfl_xor(v, off);

        if (threadIdx.x == 0) {
            const long long q64 = (long long)((double)v * FIX_SCALE);
            atomicAdd(acc, (unsigned long long)q64);
            __threadfence();
            const unsigned long long t63 = atomicAdd(ticket, 1ULL);
            if (t63 == (B_DIM * 8 - 1)) {
                const unsigned long long totu = atomicAdd(acc, 0ULL);
                const double tot_d = (double)(long long)totu / FIX_SCALE;
                out[0] = (float)(tot_d / ((double)N_DIM * (double)N_DIM * (double)B_DIM));
            }
        }
    }
}

extern "C" void kernel_launch(void* const* d_in, const int* in_sizes, int n_in,
                              void* d_out, int out_size, void* d_ws, size_t ws_size,
                              hipStream_t stream) {
    const float* x = (const float*)d_in[0];
    float* out = (float*)d_out;

    float* partial = (float*)d_ws;                                  // 8*128*512 floats = 2 MB
    unsigned long long* ctl = (unsigned long long*)((char*)d_ws +
                              (size_t)B_DIM * CHUNKS * D_DIM * sizeof(float));

    k1_partial<<<dim3(B_DIM * CHUNKS), dim3(512), 0, stream>>>(x, partial, ctl);
    k2_batch<<<dim3(B_DIM * 8), dim3(512), 0, stream>>>(partial, ctl + 0, ctl + 1, out);
}